// Round 2
// 3220.929 us; speedup vs baseline: 1.2398x; 1.2398x over previous
//
#include <hip/hip_runtime.h>
#include <hip/hip_bf16.h>
#include <stdint.h>

#define T_STEPS 256
#define BATCH   16
#define HIDDIM  1024
#define VOCAB   32000
#define TB      4096   // T_STEPS * BATCH

typedef __attribute__((ext_vector_type(8))) short  short8;
typedef __attribute__((ext_vector_type(4))) float  floatx4;

__device__ inline unsigned short f2bfu(float x) {
  __hip_bfloat16 h = __float2bfloat16(x);
  unsigned short u;
  __builtin_memcpy(&u, &h, 2);
  return u;
}
__device__ inline float bfu2f(unsigned short u) {
  __hip_bfloat16 h;
  __builtin_memcpy(&h, &u, 2);
  return __bfloat162float(h);
}

// ---------------- transpose + convert: src fp32 [K][N] -> dst bf16 [N][K] (+optional lo residual)
__global__ __launch_bounds__(256) void transpose_cvt(
    const float* __restrict__ src, unsigned short* __restrict__ dst,
    unsigned short* __restrict__ dst_lo, int K, int N) {
  __shared__ float tile[64][65];
  int n0 = blockIdx.x * 64, k0 = blockIdx.y * 64;
  int tid = threadIdx.x;
#pragma unroll
  for (int j = 0; j < 16; ++j) {
    int idx = j * 256 + tid;
    int kl = idx >> 6, nl = idx & 63;
    tile[kl][nl] = src[(size_t)(k0 + kl) * N + n0 + nl];
  }
  __syncthreads();
#pragma unroll
  for (int j = 0; j < 16; ++j) {
    int idx = j * 256 + tid;
    int nl = idx >> 6, kl = idx & 63;   // kl fast-varying -> coalesced writes along K
    float v = tile[kl][nl];
    unsigned short hi = f2bfu(v);
    dst[(size_t)(n0 + nl) * K + k0 + kl] = hi;
    if (dst_lo) dst_lo[(size_t)(n0 + nl) * K + k0 + kl] = f2bfu(v - bfu2f(hi));
  }
}

// ---------------- embedding gather + bf16 convert
__global__ __launch_bounds__(256) void gather_cvt(
    const int* __restrict__ X, const float* __restrict__ We,
    unsigned short* __restrict__ emb) {
  int r = blockIdx.x;                 // 0..4095 = t*16+b
  int row = X[r];
  int c = threadIdx.x * 4;
  float4 v = *(const float4*)(We + (size_t)row * HIDDIM + c);
  ushort4 o;
  o.x = f2bfu(v.x); o.y = f2bfu(v.y); o.z = f2bfu(v.z); o.w = f2bfu(v.w);
  *(ushort4*)(emb + (size_t)r * HIDDIM + c) = o;
}

// ---------------- bf16 MFMA GEMM: C[M][N] = A[M][K] @ BT[N][K]^T + bias, m97-style
#define BM 128
#define BN 128
#define BK 64

__device__ inline void glds16(const unsigned short* gp, unsigned short* lp) {
  __builtin_amdgcn_global_load_lds(
      (__attribute__((address_space(1))) unsigned int*)(uintptr_t)gp,
      (__attribute__((address_space(3))) unsigned int*)(unsigned int)(uintptr_t)lp,
      16, 0, 0);
}

__global__ __launch_bounds__(256) void gemm_bf16(
    const unsigned short* __restrict__ A,   // [M][K] bf16, K contiguous
    const unsigned short* __restrict__ BT,  // [N][K] bf16, K contiguous
    const float* __restrict__ bias,         // [N]
    float* __restrict__ C,                  // [M][N] fp32
    int N, int K) {
  __shared__ unsigned short As[BM * BK];
  __shared__ unsigned short Bs[BN * BK];
  int tid = threadIdx.x;
  int wave = tid >> 6, lane = tid & 63;
  int l15 = lane & 15, quad = lane >> 4;
  int m0 = blockIdx.y * BM, n0 = blockIdx.x * BN;
  int wm = (wave >> 1) * 64, wn = (wave & 1) * 64;
  int lrow = lane >> 3, lk = (lane & 7) * 8;
  floatx4 acc[4][4] = {};
  for (int kt = 0; kt < K; kt += BK) {
    __syncthreads();
#pragma unroll
    for (int i = 0; i < 4; ++i) {
      int rb = wave * 32 + i * 8;
      glds16(A  + (size_t)(m0 + rb + lrow) * K + kt + lk, As + rb * BK);
      glds16(BT + (size_t)(n0 + rb + lrow) * K + kt + lk, Bs + rb * BK);
    }
    __syncthreads();
#pragma unroll
    for (int ks = 0; ks < 2; ++ks) {
      short8 af[4], bv[4];
#pragma unroll
      for (int i = 0; i < 4; ++i)
        af[i] = *(const short8*)(As + (wm + i * 16 + l15) * BK + ks * 32 + quad * 8);
#pragma unroll
      for (int i = 0; i < 4; ++i)
        bv[i] = *(const short8*)(Bs + (wn + i * 16 + l15) * BK + ks * 32 + quad * 8);
#pragma unroll
      for (int mt = 0; mt < 4; ++mt)
#pragma unroll
        for (int nt = 0; nt < 4; ++nt)
          acc[mt][nt] = __builtin_amdgcn_mfma_f32_16x16x32_bf16(af[mt], bv[nt], acc[mt][nt], 0, 0, 0);
    }
  }
#pragma unroll
  for (int nt = 0; nt < 4; ++nt) {
    int gn = n0 + wn + nt * 16 + l15;
    float bvv = bias ? bias[gn] : 0.0f;
#pragma unroll
    for (int mt = 0; mt < 4; ++mt) {
      int gm = m0 + wm + mt * 16 + quad * 4;
#pragma unroll
      for (int r = 0; r < 4; ++r)
        C[(size_t)(gm + r) * N + gn] = acc[mt][nt][r] + bvv;
    }
  }
}

// ---------------- sequential scan: h_t = tanh(pre_t + h_{t-1} @ W_hh)
//
// Canary design (R3, hardened R4): no explicit sync ops on the critical path.
// h published as fp32 into a buffer pre-memset to 0xFF..F; fp32 tanh output
// can never be the all-ones NaN pattern, so every 8B word is self-validating.
// Producers store fire-and-forget (no s_waitcnt ack, no flag, no RELEASE ->
// no buffer_wbl2 L2-flush). Consumers fuse detect+load: reload-until-__all-
// valid; the final poll round leaves operands in registers.
//
// R4 hardening: poll guard cut 1M -> 8K rounds with s_sleep backoff after the
// first few misses. Even a total visibility failure now resolves in ~seconds
// with wrong-but-measurable output instead of a watchdog-killed container.
//
// Structure: 64 WGs x 4 waves. WG j owns output cols [16j,16j+16); wave w
// covers k in [256w, 256w+256) (A hi/lo resident: 64 VGPRs; polled B words:
// 64 VGPRs). Partial sums reduced via LDS (double-buffered, 1 barrier/step);
// wave 0 applies pre + tanh and publishes. Recurrence math identical to the
// prior hi/lo scheme (hi/lo derived from the same f32), so absmax unchanged.
#define SCAN_WGS 64
#define CANARY64 0xFFFFFFFFFFFFFFFFull

__global__ __launch_bounds__(256) void scan_kernel(
    const float* __restrict__ pre,            // [TB][HIDDIM], b_h folded in
    const unsigned short* __restrict__ WThi,  // [m=1024][k=1024]  W_hh[k][m] hi
    const unsigned short* __restrict__ WTlo,
    float* __restrict__ hf,                   // [TB][HIDDIM] f32, canary-initialized
    unsigned short* __restrict__ h_hi) {      // [TB][HIDDIM] bf16 (final GEMM input)
  int tid = threadIdx.x;
  int wave = tid >> 6, lane = tid & 63;
  int l15 = lane & 15, quad = lane >> 4;
  int wg = blockIdx.x;
  int mslice = wg * 16;
  int kbase = wave * 256;

  // A[m][k] frags: m = mslice + l15, k = kbase + kt*32 + quad*8 .. +8
  short8 Ahi[8], Alo[8];
  {
    const unsigned short* wh = WThi + (size_t)(mslice + l15) * HIDDIM + kbase + quad * 8;
    const unsigned short* wl = WTlo + (size_t)(mslice + l15) * HIDDIM + kbase + quad * 8;
#pragma unroll
    for (int kt = 0; kt < 8; ++kt) {
      Ahi[kt] = *(const short8*)(wh + kt * 32);
      Alo[kt] = *(const short8*)(wl + kt * 32);
    }
  }

  // double-buffered partial-sum exchange: [t&1][wave-1][batch][cols(+pad)]
  __shared__ float red[2][3][16][20];

  for (int t = 0; t < T_STEPS; ++t) {
    floatx4 p;
    size_t orow = 0;
    if (wave == 0) {                          // issue early; latency hides under poll
      orow = ((size_t)t * BATCH + l15) * HIDDIM + mslice + quad * 4;
      p = *(const floatx4*)(pre + orow);
    }
    floatx4 acc0 = {0.f, 0.f, 0.f, 0.f}, acc1 = {0.f, 0.f, 0.f, 0.f};
    if (t > 0) {
      // B[k][n]: n = batch = l15, k = kbase + kt*32 + quad*8 .. +8  (fp32)
      const unsigned long long* bp = (const unsigned long long*)
          (hf + ((size_t)(t - 1) * BATCH + l15) * HIDDIM + kbase + quad * 8);
      unsigned long long Bw[32];
      int guard = 0;
      bool ok;
      do {                                    // fused detect+load: data is the flag
        ok = true;
#pragma unroll
        for (int kt = 0; kt < 8; ++kt)
#pragma unroll
          for (int j = 0; j < 4; ++j) {
            unsigned long long w = __hip_atomic_load(bp + (size_t)kt * 16 + j,
                __ATOMIC_RELAXED, __HIP_MEMORY_SCOPE_AGENT);
            Bw[kt * 4 + j] = w;
            ok &= (w != CANARY64);
          }
        if (__all(ok)) break;
        ++guard;
        if (guard > 4) __builtin_amdgcn_s_sleep(1);   // backoff: cut IC hammering
      } while (guard <= 8192);                // bounded failsafe: fast-fail, no hang
      // convert f32 -> bf16 hi/lo (identical rounding to stored-hi/lo scheme)
#pragma unroll
      for (int kt = 0; kt < 8; ++kt) {
        short8 bh, bl;
#pragma unroll
        for (int j = 0; j < 4; ++j) {
          unsigned long long w = Bw[kt * 4 + j];
          unsigned int u0 = (unsigned int)w, u1 = (unsigned int)(w >> 32);
          float f0 = __uint_as_float(u0), f1 = __uint_as_float(u1);
          unsigned short h0 = f2bfu(f0), h1 = f2bfu(f1);
          bh[2 * j]     = (short)h0;
          bh[2 * j + 1] = (short)h1;
          bl[2 * j]     = (short)f2bfu(f0 - bfu2f(h0));
          bl[2 * j + 1] = (short)f2bfu(f1 - bfu2f(h1));
        }
        // split accumulators: dependent MFMA chain 16 (acc0) + 8 (acc1)
        acc0 = __builtin_amdgcn_mfma_f32_16x16x32_bf16(Ahi[kt], bh, acc0, 0, 0, 0);
        acc1 = __builtin_amdgcn_mfma_f32_16x16x32_bf16(Alo[kt], bh, acc1, 0, 0, 0);
        acc0 = __builtin_amdgcn_mfma_f32_16x16x32_bf16(Ahi[kt], bl, acc0, 0, 0, 0);
      }
    }
    if (wave > 0) {
      floatx4 s = acc0 + acc1;                // acc element r = (m=quad*4+r, n=l15)
      *(floatx4*)&red[t & 1][wave - 1][l15][quad * 4] = s;
    }
    __syncthreads();                          // single barrier/step (red dbl-buffered)
    if (wave == 0) {
      floatx4 r0 = *(const floatx4*)&red[t & 1][0][l15][quad * 4];
      floatx4 r1 = *(const floatx4*)&red[t & 1][1][l15][quad * 4];
      floatx4 r2 = *(const floatx4*)&red[t & 1][2][l15][quad * 4];
      float th0 = tanhf(acc0[0] + acc1[0] + r0[0] + r1[0] + r2[0] + p[0]);
      float th1 = tanhf(acc0[1] + acc1[1] + r0[1] + r1[1] + r2[1] + p[1]);
      float th2 = tanhf(acc0[2] + acc1[2] + r0[2] + r1[2] + r2[2] + p[2]);
      float th3 = tanhf(acc0[3] + acc1[3] + r0[3] + r1[3] + r2[3] + p[3]);
      // publish fp32 h: fire-and-forget self-validating stores (no waitcnt/flag)
      union { float f[2]; unsigned long long u; } a, b;
      a.f[0] = th0; a.f[1] = th1; b.f[0] = th2; b.f[1] = th3;
      unsigned long long* hp = (unsigned long long*)(hf + orow);
      __hip_atomic_store(hp,     a.u, __ATOMIC_RELAXED, __HIP_MEMORY_SCOPE_AGENT);
      __hip_atomic_store(hp + 1, b.u, __ATOMIC_RELAXED, __HIP_MEMORY_SCOPE_AGENT);
      // bf16 copy for the final GEMM (plain store; kernel boundary publishes it)
      ushort4 sh;
      sh.x = f2bfu(th0); sh.y = f2bfu(th1); sh.z = f2bfu(th2); sh.w = f2bfu(th3);
      *(ushort4*)(h_hi + orow) = sh;
    }
  }
}

extern "C" void kernel_launch(void* const* d_in, const int* in_sizes, int n_in,
                              void* d_out, int out_size, void* d_ws, size_t ws_size,
                              hipStream_t stream) {
  const int*   X    = (const int*)d_in[0];
  const float* W_e  = (const float*)d_in[1];
  const float* W_xh = (const float*)d_in[2];
  const float* W_hh = (const float*)d_in[3];
  const float* b_h  = (const float*)d_in[4];
  const float* W_hq = (const float*)d_in[5];
  const float* b_q  = (const float*)d_in[6];
  float* out = (float*)d_out;

  char* w = (char*)d_ws;                                      // total used: ~113.8 MB
  unsigned short* WhqT   = (unsigned short*)(w + 0);          // 65,536,000  [32000][1024]
  unsigned short* WxhT   = (unsigned short*)(w + 65536000);   //  2,097,152  [1024][1024]
  unsigned short* WhhThi = (unsigned short*)(w + 67633152);   //  2,097,152
  unsigned short* WhhTlo = (unsigned short*)(w + 69730304);   //  2,097,152
  unsigned short* emb    = (unsigned short*)(w + 71827456);   //  8,388,608  [4096][1024]
  float*          pre    = (float*)        (w + 80216064);    // 16,777,216  [4096][1024]
  float*          hf     = (float*)        (w + 96993280);    // 16,777,216  [4096][1024] f32
  unsigned short* h_hi   = emb;  // alias: emb dead after pre-GEMM (stream-ordered)

  // canary-init hf: fp32 tanh output can never be the all-ones NaN pattern
  hipMemsetAsync(hf, 0xFF, (size_t)TB * HIDDIM * sizeof(float), stream);
  transpose_cvt<<<dim3(VOCAB / 64, HIDDIM / 64), 256, 0, stream>>>(W_hq, WhqT, nullptr, HIDDIM, VOCAB);
  transpose_cvt<<<dim3(HIDDIM / 64, HIDDIM / 64), 256, 0, stream>>>(W_xh, WxhT, nullptr, HIDDIM, HIDDIM);
  transpose_cvt<<<dim3(HIDDIM / 64, HIDDIM / 64), 256, 0, stream>>>(W_hh, WhhThi, WhhTlo, HIDDIM, HIDDIM);
  gather_cvt<<<TB, 256, 0, stream>>>(X, W_e, emb);
  gemm_bf16<<<dim3(HIDDIM / BN, TB / BM), 256, 0, stream>>>(emb, WxhT, b_h, pre, HIDDIM, HIDDIM);
  scan_kernel<<<SCAN_WGS, 256, 0, stream>>>(pre, WhhThi, WhhTlo, hf, h_hi);
  gemm_bf16<<<dim3(VOCAB / BN, TB / BM), 256, 0, stream>>>(h_hi, WhqT, b_q, out, VOCAB, HIDDIM);
}

// Round 3
// 3212.923 us; speedup vs baseline: 1.2429x; 1.0025x over previous
//
#include <hip/hip_runtime.h>
#include <hip/hip_bf16.h>
#include <stdint.h>

#define T_STEPS 256
#define BATCH   16
#define HIDDIM  1024
#define VOCAB   32000
#define TB      4096   // T_STEPS * BATCH

typedef __attribute__((ext_vector_type(8))) short  short8;
typedef __attribute__((ext_vector_type(4))) float  floatx4;

__device__ inline unsigned short f2bfu(float x) {
  __hip_bfloat16 h = __float2bfloat16(x);
  unsigned short u;
  __builtin_memcpy(&u, &h, 2);
  return u;
}
__device__ inline float bfu2f(unsigned short u) {
  __hip_bfloat16 h;
  __builtin_memcpy(&h, &u, 2);
  return __bfloat162float(h);
}

// ---------------- transpose + convert: src fp32 [K][N] -> dst bf16 [N][K] (+optional lo residual)
__global__ __launch_bounds__(256) void transpose_cvt(
    const float* __restrict__ src, unsigned short* __restrict__ dst,
    unsigned short* __restrict__ dst_lo, int K, int N) {
  __shared__ float tile[64][65];
  int n0 = blockIdx.x * 64, k0 = blockIdx.y * 64;
  int tid = threadIdx.x;
#pragma unroll
  for (int j = 0; j < 16; ++j) {
    int idx = j * 256 + tid;
    int kl = idx >> 6, nl = idx & 63;
    tile[kl][nl] = src[(size_t)(k0 + kl) * N + n0 + nl];
  }
  __syncthreads();
#pragma unroll
  for (int j = 0; j < 16; ++j) {
    int idx = j * 256 + tid;
    int nl = idx >> 6, kl = idx & 63;   // kl fast-varying -> coalesced writes along K
    float v = tile[kl][nl];
    unsigned short hi = f2bfu(v);
    dst[(size_t)(n0 + nl) * K + k0 + kl] = hi;
    if (dst_lo) dst_lo[(size_t)(n0 + nl) * K + k0 + kl] = f2bfu(v - bfu2f(hi));
  }
}

// ---------------- embedding gather + bf16 convert
__global__ __launch_bounds__(256) void gather_cvt(
    const int* __restrict__ X, const float* __restrict__ We,
    unsigned short* __restrict__ emb) {
  int r = blockIdx.x;                 // 0..4095 = t*16+b
  int row = X[r];
  int c = threadIdx.x * 4;
  float4 v = *(const float4*)(We + (size_t)row * HIDDIM + c);
  ushort4 o;
  o.x = f2bfu(v.x); o.y = f2bfu(v.y); o.z = f2bfu(v.z); o.w = f2bfu(v.w);
  *(ushort4*)(emb + (size_t)r * HIDDIM + c) = o;
}

// ---------------- bf16 MFMA GEMM: C[M][N] = A[M][K] @ BT[N][K]^T + bias, m97-style
#define BM 128
#define BN 128
#define BK 64

__device__ inline void glds16(const unsigned short* gp, unsigned short* lp) {
  __builtin_amdgcn_global_load_lds(
      (__attribute__((address_space(1))) unsigned int*)(uintptr_t)gp,
      (__attribute__((address_space(3))) unsigned int*)(unsigned int)(uintptr_t)lp,
      16, 0, 0);
}

__global__ __launch_bounds__(256) void gemm_bf16(
    const unsigned short* __restrict__ A,   // [M][K] bf16, K contiguous
    const unsigned short* __restrict__ BT,  // [N][K] bf16, K contiguous
    const float* __restrict__ bias,         // [N]
    float* __restrict__ C,                  // [M][N] fp32
    int N, int K) {
  __shared__ unsigned short As[BM * BK];
  __shared__ unsigned short Bs[BN * BK];
  int tid = threadIdx.x;
  int wave = tid >> 6, lane = tid & 63;
  int l15 = lane & 15, quad = lane >> 4;
  int m0 = blockIdx.y * BM, n0 = blockIdx.x * BN;
  int wm = (wave >> 1) * 64, wn = (wave & 1) * 64;
  int lrow = lane >> 3, lk = (lane & 7) * 8;
  floatx4 acc[4][4] = {};
  for (int kt = 0; kt < K; kt += BK) {
    __syncthreads();
#pragma unroll
    for (int i = 0; i < 4; ++i) {
      int rb = wave * 32 + i * 8;
      glds16(A  + (size_t)(m0 + rb + lrow) * K + kt + lk, As + rb * BK);
      glds16(BT + (size_t)(n0 + rb + lrow) * K + kt + lk, Bs + rb * BK);
    }
    __syncthreads();
#pragma unroll
    for (int ks = 0; ks < 2; ++ks) {
      short8 af[4], bv[4];
#pragma unroll
      for (int i = 0; i < 4; ++i)
        af[i] = *(const short8*)(As + (wm + i * 16 + l15) * BK + ks * 32 + quad * 8);
#pragma unroll
      for (int i = 0; i < 4; ++i)
        bv[i] = *(const short8*)(Bs + (wn + i * 16 + l15) * BK + ks * 32 + quad * 8);
#pragma unroll
      for (int mt = 0; mt < 4; ++mt)
#pragma unroll
        for (int nt = 0; nt < 4; ++nt)
          acc[mt][nt] = __builtin_amdgcn_mfma_f32_16x16x32_bf16(af[mt], bv[nt], acc[mt][nt], 0, 0, 0);
    }
  }
#pragma unroll
  for (int nt = 0; nt < 4; ++nt) {
    int gn = n0 + wn + nt * 16 + l15;
    float bvv = bias ? bias[gn] : 0.0f;
#pragma unroll
    for (int mt = 0; mt < 4; ++mt) {
      int gm = m0 + wm + mt * 16 + quad * 4;
#pragma unroll
      for (int r = 0; r < 4; ++r)
        C[(size_t)(gm + r) * N + gn] = acc[mt][nt][r] + bvv;
    }
  }
}

// ---------------- sequential scan: h_t = tanh(pre_t + h_{t-1} @ W_hh)
//
// Canary design (R3/R4) + R5 scope fix.
//
// R4 post-mortem: scan 2900->2140us only (predicted ~700). FETCH_SIZE 155MB
// = 64KB(h) x 8 XCDs + pre per step => poll re-rounds were served by STALE
// per-XCD L2 lines (agent-scope sc1 loads allocate in L2 on this silicon);
// detection waited on IC->L2 invalidate propagation (~6us/step, the wall).
//
// R5: SYSTEM-scope atomics (sc0 sc1) for h publish + poll. Loads bypass
// L1+L2 and read the IC directly every round; stores push to IC without
// leaving an L2 line for the invalidation protocol to chase. Detection =
// one IC read latency after the store lands. Predicted ~2us/step.
// (Direct counter test: FETCH_SIZE should jump 155MB -> multi-GB since every
// round now reaches EA. If FETCH jumps but dur doesn't drop, the wall is
// store-drain-to-IC, not L2 staleness.)
//
// Structure: 64 WGs x 4 waves. WG j owns output cols [16j,16j+16); wave w
// covers k in [256w, 256w+256) (A hi/lo resident: 64 VGPRs; polled B words:
// 64 VGPRs). Partial sums reduced via LDS (double-buffered, 1 barrier/step);
// wave 0 applies pre + tanh and publishes. Recurrence math identical to the
// prior hi/lo scheme (hi/lo derived from the same f32), so absmax unchanged.
#define SCAN_WGS 64
#define CANARY64 0xFFFFFFFFFFFFFFFFull

__global__ __launch_bounds__(256) void scan_kernel(
    const float* __restrict__ pre,            // [TB][HIDDIM], b_h folded in
    const unsigned short* __restrict__ WThi,  // [m=1024][k=1024]  W_hh[k][m] hi
    const unsigned short* __restrict__ WTlo,
    float* __restrict__ hf,                   // [TB][HIDDIM] f32, canary-initialized
    unsigned short* __restrict__ h_hi) {      // [TB][HIDDIM] bf16 (final GEMM input)
  int tid = threadIdx.x;
  int wave = tid >> 6, lane = tid & 63;
  int l15 = lane & 15, quad = lane >> 4;
  int wg = blockIdx.x;
  int mslice = wg * 16;
  int kbase = wave * 256;

  // A[m][k] frags: m = mslice + l15, k = kbase + kt*32 + quad*8 .. +8
  short8 Ahi[8], Alo[8];
  {
    const unsigned short* wh = WThi + (size_t)(mslice + l15) * HIDDIM + kbase + quad * 8;
    const unsigned short* wl = WTlo + (size_t)(mslice + l15) * HIDDIM + kbase + quad * 8;
#pragma unroll
    for (int kt = 0; kt < 8; ++kt) {
      Ahi[kt] = *(const short8*)(wh + kt * 32);
      Alo[kt] = *(const short8*)(wl + kt * 32);
    }
  }

  // double-buffered partial-sum exchange: [t&1][wave-1][batch][cols(+pad)]
  __shared__ float red[2][3][16][20];

  for (int t = 0; t < T_STEPS; ++t) {
    floatx4 p;
    size_t orow = 0;
    if (wave == 0) {                          // issue early; latency hides under poll
      orow = ((size_t)t * BATCH + l15) * HIDDIM + mslice + quad * 4;
      p = *(const floatx4*)(pre + orow);
    }
    floatx4 acc0 = {0.f, 0.f, 0.f, 0.f}, acc1 = {0.f, 0.f, 0.f, 0.f};
    if (t > 0) {
      // B[k][n]: n = batch = l15, k = kbase + kt*32 + quad*8 .. +8  (fp32)
      const unsigned long long* bp = (const unsigned long long*)
          (hf + ((size_t)(t - 1) * BATCH + l15) * HIDDIM + kbase + quad * 8);
      unsigned long long Bw[32];
      int guard = 0;
      bool ok;
      do {                                    // fused detect+load: data is the flag
        ok = true;
#pragma unroll
        for (int kt = 0; kt < 8; ++kt)
#pragma unroll
          for (int j = 0; j < 4; ++j) {
            unsigned long long w = __hip_atomic_load(bp + (size_t)kt * 16 + j,
                __ATOMIC_RELAXED, __HIP_MEMORY_SCOPE_SYSTEM);   // sc0 sc1: bypass L2, read IC
            Bw[kt * 4 + j] = w;
            ok &= (w != CANARY64);
          }
        if (__all(ok)) break;
        ++guard;
        if (guard > 4) __builtin_amdgcn_s_sleep(1);   // backoff: cut IC hammering
      } while (guard <= 8192);                // bounded failsafe: fast-fail, no hang
      // convert f32 -> bf16 hi/lo (identical rounding to stored-hi/lo scheme)
#pragma unroll
      for (int kt = 0; kt < 8; ++kt) {
        short8 bh, bl;
#pragma unroll
        for (int j = 0; j < 4; ++j) {
          unsigned long long w = Bw[kt * 4 + j];
          unsigned int u0 = (unsigned int)w, u1 = (unsigned int)(w >> 32);
          float f0 = __uint_as_float(u0), f1 = __uint_as_float(u1);
          unsigned short h0 = f2bfu(f0), h1 = f2bfu(f1);
          bh[2 * j]     = (short)h0;
          bh[2 * j + 1] = (short)h1;
          bl[2 * j]     = (short)f2bfu(f0 - bfu2f(h0));
          bl[2 * j + 1] = (short)f2bfu(f1 - bfu2f(h1));
        }
        // split accumulators: dependent MFMA chain 16 (acc0) + 8 (acc1)
        acc0 = __builtin_amdgcn_mfma_f32_16x16x32_bf16(Ahi[kt], bh, acc0, 0, 0, 0);
        acc1 = __builtin_amdgcn_mfma_f32_16x16x32_bf16(Alo[kt], bh, acc1, 0, 0, 0);
        acc0 = __builtin_amdgcn_mfma_f32_16x16x32_bf16(Ahi[kt], bl, acc0, 0, 0, 0);
      }
    }
    if (wave > 0) {
      floatx4 s = acc0 + acc1;                // acc element r = (m=quad*4+r, n=l15)
      *(floatx4*)&red[t & 1][wave - 1][l15][quad * 4] = s;
    }
    __syncthreads();                          // single barrier/step (red dbl-buffered)
    if (wave == 0) {
      floatx4 r0 = *(const floatx4*)&red[t & 1][0][l15][quad * 4];
      floatx4 r1 = *(const floatx4*)&red[t & 1][1][l15][quad * 4];
      floatx4 r2 = *(const floatx4*)&red[t & 1][2][l15][quad * 4];
      float th0 = tanhf(acc0[0] + acc1[0] + r0[0] + r1[0] + r2[0] + p[0]);
      float th1 = tanhf(acc0[1] + acc1[1] + r0[1] + r1[1] + r2[1] + p[1]);
      float th2 = tanhf(acc0[2] + acc1[2] + r0[2] + r1[2] + r2[2] + p[2]);
      float th3 = tanhf(acc0[3] + acc1[3] + r0[3] + r1[3] + r2[3] + p[3]);
      // publish fp32 h: fire-and-forget self-validating stores, SYSTEM scope
      // (sc0 sc1: push to IC, no L2 line left behind)
      union { float f[2]; unsigned long long u; } a, b;
      a.f[0] = th0; a.f[1] = th1; b.f[0] = th2; b.f[1] = th3;
      unsigned long long* hp = (unsigned long long*)(hf + orow);
      __hip_atomic_store(hp,     a.u, __ATOMIC_RELAXED, __HIP_MEMORY_SCOPE_SYSTEM);
      __hip_atomic_store(hp + 1, b.u, __ATOMIC_RELAXED, __HIP_MEMORY_SCOPE_SYSTEM);
      // bf16 copy for the final GEMM (plain store; kernel boundary publishes it)
      ushort4 sh;
      sh.x = f2bfu(th0); sh.y = f2bfu(th1); sh.z = f2bfu(th2); sh.w = f2bfu(th3);
      *(ushort4*)(h_hi + orow) = sh;
    }
  }
}

extern "C" void kernel_launch(void* const* d_in, const int* in_sizes, int n_in,
                              void* d_out, int out_size, void* d_ws, size_t ws_size,
                              hipStream_t stream) {
  const int*   X    = (const int*)d_in[0];
  const float* W_e  = (const float*)d_in[1];
  const float* W_xh = (const float*)d_in[2];
  const float* W_hh = (const float*)d_in[3];
  const float* b_h  = (const float*)d_in[4];
  const float* W_hq = (const float*)d_in[5];
  const float* b_q  = (const float*)d_in[6];
  float* out = (float*)d_out;

  char* w = (char*)d_ws;                                      // total used: ~113.8 MB
  unsigned short* WhqT   = (unsigned short*)(w + 0);          // 65,536,000  [32000][1024]
  unsigned short* WxhT   = (unsigned short*)(w + 65536000);   //  2,097,152  [1024][1024]
  unsigned short* WhhThi = (unsigned short*)(w + 67633152);   //  2,097,152
  unsigned short* WhhTlo = (unsigned short*)(w + 69730304);   //  2,097,152
  unsigned short* emb    = (unsigned short*)(w + 71827456);   //  8,388,608  [4096][1024]
  float*          pre    = (float*)        (w + 80216064);    // 16,777,216  [4096][1024]
  float*          hf     = (float*)        (w + 96993280);    // 16,777,216  [4096][1024] f32
  unsigned short* h_hi   = emb;  // alias: emb dead after pre-GEMM (stream-ordered)

  // canary-init hf: fp32 tanh output can never be the all-ones NaN pattern
  hipMemsetAsync(hf, 0xFF, (size_t)TB * HIDDIM * sizeof(float), stream);
  transpose_cvt<<<dim3(VOCAB / 64, HIDDIM / 64), 256, 0, stream>>>(W_hq, WhqT, nullptr, HIDDIM, VOCAB);
  transpose_cvt<<<dim3(HIDDIM / 64, HIDDIM / 64), 256, 0, stream>>>(W_xh, WxhT, nullptr, HIDDIM, HIDDIM);
  transpose_cvt<<<dim3(HIDDIM / 64, HIDDIM / 64), 256, 0, stream>>>(W_hh, WhhThi, WhhTlo, HIDDIM, HIDDIM);
  gather_cvt<<<TB, 256, 0, stream>>>(X, W_e, emb);
  gemm_bf16<<<dim3(HIDDIM / BN, TB / BM), 256, 0, stream>>>(emb, WxhT, b_h, pre, HIDDIM, HIDDIM);
  scan_kernel<<<SCAN_WGS, 256, 0, stream>>>(pre, WhhThi, WhhTlo, hf, h_hi);
  gemm_bf16<<<dim3(VOCAB / BN, TB / BM), 256, 0, stream>>>(h_hi, WhqT, b_q, out, VOCAB, HIDDIM);
}